// Round 9
// baseline (5782.369 us; speedup 1.0000x reference)
//
#include <hip/hip_runtime.h>
#include <hip/hip_bf16.h>
#include <stdint.h>

// B=8192, D=2048, M=8, C=1000; padded: CPAD=1024, NPAD=8192 (n' = c*8 + m)
#define BDIM 8192
#define DDIM 2048
#define MDIM 8
#define CDIM 1000
#define CPAD 1024
#define NPAD 8192

typedef __attribute__((ext_vector_type(8))) short bf16x8;
typedef __attribute__((ext_vector_type(4))) float f32x4;

__device__ __forceinline__ unsigned short f2bf(float f) {
    union { float f; unsigned u; } v; v.f = f;
    unsigned r = v.u + 0x7fffu + ((v.u >> 16) & 1u);   // RNE
    return (unsigned short)(r >> 16);
}

__device__ __forceinline__ void gl_lds16(const void* g, void* l) {
    __builtin_amdgcn_global_load_lds(
        (const __attribute__((address_space(1))) void*)g,
        (__attribute__((address_space(3))) void*)l,
        16, 0, 0);
}

// ---------------- prep: cast x (fp32 -> bf16) ----------------
__global__ void cast_x_kernel(const float4* __restrict__ x, ushort* __restrict__ xb) {
    int i = blockIdx.x * blockDim.x + threadIdx.x;
    float4 v = x[i];
    ushort4 o;
    o.x = f2bf(v.x); o.y = f2bf(v.y); o.z = f2bf(v.z); o.w = f2bf(v.w);
    *(ushort4*)&xb[(size_t)i * 4] = o;
}

// ---- prep: model_weights (M,D,C) -> wb[n'=c*8+m][d], zero-pad c>=1000 ----
__global__ void prep_w(const float* __restrict__ MW, ushort* __restrict__ wb) {
    __shared__ float tile[32][33];
    int m  = blockIdx.z;
    int c0 = blockIdx.x * 32;
    int d0 = blockIdx.y * 32;
    int tx = threadIdx.x, ty = threadIdx.y;
    const float* src = MW + (size_t)m * DDIM * CDIM;
#pragma unroll
    for (int i = 0; i < 4; i++) {
        int d = d0 + ty + i * 8;
        int c = c0 + tx;
        tile[ty + i * 8][tx] = (c < CDIM) ? src[(size_t)d * CDIM + c] : 0.f;
    }
    __syncthreads();
#pragma unroll
    for (int i = 0; i < 4; i++) {
        int c = c0 + ty + i * 8;
        int d = d0 + tx;
        wb[(size_t)(c * 8 + m) * DDIM + d] = f2bf(tile[tx][ty + i * 8]);
    }
}

// ---- prep: resnet_weight (D, 8000) -> rb[n'=c*8+m][d], zero-pad c>=1000 ----
__global__ void prep_r(const float* __restrict__ R, ushort* __restrict__ rb) {
    __shared__ float tile[32][33];
    int m  = blockIdx.z;
    int c0 = blockIdx.x * 32;
    int d0 = blockIdx.y * 32;
    int tx = threadIdx.x, ty = threadIdx.y;
#pragma unroll
    for (int i = 0; i < 4; i++) {
        int d = d0 + ty + i * 8;
        int c = c0 + tx;
        tile[ty + i * 8][tx] = (c < CDIM) ? R[(size_t)d * (MDIM * CDIM) + m * CDIM + c] : 0.f;
    }
    __syncthreads();
#pragma unroll
    for (int i = 0; i < 4; i++) {
        int c = c0 + ty + i * 8;
        int d = d0 + tx;
        rb[(size_t)(c * 8 + m) * DDIM + d] = f2bf(tile[tx][ty + i * 8]);
    }
}

// ---- prep: biases -> interleaved padded float arrays [NPAD] ----
__global__ void prep_bias(const float* __restrict__ mb, const float* __restrict__ rbv,
                          float* __restrict__ mb2, float* __restrict__ rb2) {
    int n = blockIdx.x * 256 + threadIdx.x;   // 0..8191
    int c = n >> 3, m = n & 7;
    mb2[n] = (c < CDIM) ? mb[m * CDIM + c] : 0.f;
    rb2[n] = (c < CDIM) ? rbv[m * CDIM + c] : 0.f;
}

// --- fused dual-B GEMM: BK=32, 64KB LDS, 2 blocks/CU, 2-phase K-tile ---
#define BM 256
#define BN 128
#define BK 32
#define NT (DDIM / BK)   // 64

// Row-major LDS rows of 32 ushorts (64B = 4 x 16B chunks).
// Swizzle: slot = cc ^ ((row>>1)&3)  -> 8 bank-slot positions x 2-way per
// 16-lane group (free). Staged via inverse-swizzled global source.

// A-unit: 256 rows x 32 ushorts = 16KB, 2 insts/thread.
#define STAGE_A(G, L) do {                                                     \
    _Pragma("unroll")                                                          \
    for (int it_ = 0; it_ < 2; ++it_) {                                        \
        int ci_ = it_ * 512 + tid;                                             \
        int r_ = ci_ >> 2, cc_ = ci_ & 3;                                      \
        gl_lds16((G) + (size_t)r_ * DDIM + (size_t)((cc_ ^ ((r_ >> 1) & 3)) << 3), \
                 (L) + (size_t)(it_ * 512 + wbase) * 8);                       \
    }                                                                          \
} while (0)

// B-unit: 128 rows x 32 ushorts = 8KB, 1 inst/thread.
#define STAGE_B(G, L) do {                                                     \
    int r_ = tid >> 2, cc_ = tid & 3;                                          \
    gl_lds16((G) + (size_t)r_ * DDIM + (size_t)((cc_ ^ ((r_ >> 1) & 3)) << 3), \
             (L) + (size_t)wbase * 8);                                         \
} while (0)

// A frags for row-half H (4 x 16-row frags); 16x16x32: cc = lane>>4.
#define LDA4(AC, H) do {                                                       \
    _Pragma("unroll")                                                          \
    for (int i_ = 0; i_ < 4; i_++) {                                           \
        int row_ = wm * 128 + (H) * 64 + i_ * 16 + (lane & 15);                \
        int cc_ = lane >> 4;                                                   \
        af[i_] = *(const bf16x8*)&(AC)[row_ * BK + ((cc_ ^ ((row_ >> 1) & 3)) << 3)]; \
    }                                                                          \
} while (0)

#define LDB2(BS, BF) do {                                                      \
    _Pragma("unroll")                                                          \
    for (int j_ = 0; j_ < 2; j_++) {                                           \
        int row_ = wn * 32 + j_ * 16 + (lane & 15);                            \
        int cc_ = lane >> 4;                                                   \
        BF[j_] = *(const bf16x8*)&(BS)[row_ * BK + ((cc_ ^ ((row_ >> 1) & 3)) << 3)]; \
    }                                                                          \
} while (0)

// 16 MFMA: both accs, row-half H (frags 0-3 of af), both j
#define MM16(H) do {                                                           \
    __builtin_amdgcn_s_setprio(1);                                             \
    _Pragma("unroll")                                                          \
    for (int i_ = 0; i_ < 4; i_++)                                             \
    _Pragma("unroll")                                                          \
    for (int j_ = 0; j_ < 2; j_++) {                                           \
        acc1[(H) * 4 + i_][j_] = __builtin_amdgcn_mfma_f32_16x16x32_bf16(      \
            af[i_], bf1[j_], acc1[(H) * 4 + i_][j_], 0, 0, 0);                 \
        acc2[(H) * 4 + i_][j_] = __builtin_amdgcn_mfma_f32_16x16x32_bf16(      \
            af[i_], bf2[j_], acc2[(H) * 4 + i_][j_], 0, 0, 0);                 \
    }                                                                          \
    __builtin_amdgcn_s_setprio(0);                                             \
} while (0)

#define FENCE() asm volatile("" ::: "memory")
#define BARRIER() do { FENCE(); __builtin_amdgcn_s_barrier(); FENCE(); } while (0)
#define WAITV(N) asm volatile("s_waitcnt vmcnt(" #N ")" ::: "memory")

__global__ __launch_bounds__(512, 4) void gemm_fused(
    const ushort* __restrict__ xb, const ushort* __restrict__ wb,
    const ushort* __restrict__ rb,
    const float* __restrict__ mb2, const float* __restrict__ rb2,
    float* __restrict__ out) {
    __shared__ ushort As[2][BM * BK];    // 2 x 16 KB
    __shared__ ushort B1s[2][BN * BK];   // 2 x 8 KB
    __shared__ ushort B2s[2][BN * BK];   // 2 x 8 KB   -> 64 KB total

    int tid   = threadIdx.x;
    int lane  = tid & 63;
    int wid   = tid >> 6;        // 0..7
    int wm    = wid >> 2;        // 0..1 -> 128-row half
    int wn    = wid & 3;         // 0..3 -> 32-col quarter
    int wbase = tid & ~63;

    // T1: bijective XCD swizzle (2048 % 8 == 0)
    int wg = blockIdx.x;
    int wgs = (wg & 7) * 256 + (wg >> 3);
    int tile_m = wgs >> 6;       // 0..31
    int tile_n = wgs & 63;       // 0..63
    int brow = tile_m * BM;
    int bn0  = tile_n * BN;

    const ushort* xg  = xb + (size_t)brow * DDIM;
    const ushort* w1g = wb + (size_t)bn0 * DDIM;
    const ushort* w2g = rb + (size_t)bn0 * DDIM;

    f32x4 acc1[8][2] = {};
    f32x4 acc2[8][2] = {};
    bf16x8 af[4], bf1[2], bf2[2];

    // Units/K-tile: A (2 insts), B1 (1), B2 (1).
    // Prologue: A(0),B1(0),B2(0),A(1); drain all but A(1).
    STAGE_A(xg,        As[0]);
    STAGE_B(w1g,       B1s[0]);
    STAGE_B(w2g,       B2s[0]);
    STAGE_A(xg + BK,   As[1]);
    WAITV(2);                 // leaves [A(1)] — loop invariant
    BARRIER();

    // Per K-tile t (invariant at top: outstanding = A(t+1), 2 insts):
    //  P1: read af-h0(4), bf1(2), bf2(2) | stage B1,B2(t+1) | bar | 16 MFMA | bar
    //  P2: read af-h1(4)                 | stage A(t+2)     | bar | 16 MFMA
    //      | WAITV(2): drains A(t+1),B1(t+1),B2(t+1), leaves A(t+2) | bar
    // Tail stages read in-bounds garbage (tiles NT/NT+1), never consumed.
#pragma unroll 2
    for (int t = 0; t < NT; ++t) {
        int buf = t & 1;
        ushort* Ac  = As[buf];
        ushort* B1c = B1s[buf];
        ushort* B2c = B2s[buf];
        ushort* B1n = B1s[buf ^ 1];
        ushort* B2n = B2s[buf ^ 1];
        const int kn  = (t + 1) * BK;
        const int kn2 = (t + 2) * BK;

        // P1
        LDA4(Ac, 0);
        LDB2(B1c, bf1);
        LDB2(B2c, bf2);
        STAGE_B(w1g + kn, B1n);
        STAGE_B(w2g + kn, B2n);
        BARRIER();
        MM16(0);
        BARRIER();

        // P2
        LDA4(Ac, 1);
        STAGE_A(xg + kn2, Ac);   // A(t+2) overwrites As[buf]; safe: all tile-t
                                 // A-reads retired before end of P1's MFMA
        BARRIER();
        MM16(1);
        WAITV(2);                // drains A(t+1),B1(t+1),B2(t+1)
        BARRIER();
    }
    WAITV(0);  // garbage-stage DMA must not outlive this workgroup's LDS

    // ---- epilogue: p = (acc1+b1)(acc2+b2); reduce over m (8 adjacent n');
    // n' = c*8 + m -> 3x shfl_xor; plain stores, disjoint per block.
    // acc rf = H*4+i -> tile row = wm*128 + rf*16 + frag row ----
#pragma unroll
    for (int j = 0; j < 2; j++) {
        int np = bn0 + wn * 32 + j * 16 + (lane & 15);
        float bb1 = mb2[np];
        float bb2 = rb2[np];
        int c = tile_n * 16 + wn * 4 + j * 2 + ((lane >> 3) & 1);
#pragma unroll
        for (int rf = 0; rf < 8; rf++) {
#pragma unroll
            for (int r = 0; r < 4; r++) {
                float p = (acc1[rf][j][r] + bb1) * (acc2[rf][j][r] + bb2);
                p += __shfl_xor(p, 1);
                p += __shfl_xor(p, 2);
                p += __shfl_xor(p, 4);
                if ((lane & 7) == 0 && c < CDIM) {
                    int row = brow + wm * 128 + rf * 16 + ((lane >> 4) << 2) + r;
                    out[(size_t)row * CDIM + c] = p;
                }
            }
        }
    }
}

extern "C" void kernel_launch(void* const* d_in, const int* in_sizes, int n_in,
                              void* d_out, int out_size, void* d_ws, size_t ws_size,
                              hipStream_t stream) {
    const float* x   = (const float*)d_in[0];   // [8192][2048]
    const float* mw  = (const float*)d_in[1];   // [8][2048][1000]
    const float* mb  = (const float*)d_in[2];   // [8][1000]
    const float* rw  = (const float*)d_in[3];   // [2048][8000]
    const float* rbv = (const float*)d_in[4];   // [8000]
    float* out = (float*)d_out;                 // [8192][1000]

    char* ws = (char*)d_ws;
    ushort* xb  = (ushort*)ws;                                  // 33,554,432 B
    ushort* wb  = (ushort*)(ws + (size_t)33554432);             // 33,554,432 B
    ushort* rb  = (ushort*)(ws + (size_t)67108864);             // 33,554,432 B
    float*  mb2 = (float*)(ws + (size_t)100663296);             // 32,768 B
    float*  rb2 = (float*)(ws + (size_t)100696064);             // 32,768 B

    cast_x_kernel<<<BDIM * DDIM / (256 * 4), 256, 0, stream>>>((const float4*)x, xb);
    prep_w<<<dim3(CPAD / 32, DDIM / 32, MDIM), dim3(32, 8), 0, stream>>>(mw, wb);
    prep_r<<<dim3(CPAD / 32, DDIM / 32, MDIM), dim3(32, 8), 0, stream>>>(rw, rb);
    prep_bias<<<NPAD / 256, 256, 0, stream>>>(mb, rbv, mb2, rb2);

    gemm_fused<<<dim3((BDIM / BM) * (NPAD / BN)), 512, 0, stream>>>(xb, wb, rb, mb2, rb2, out);
}

// Round 10
// 641.725 us; speedup vs baseline: 9.0107x; 9.0107x over previous
//
#include <hip/hip_runtime.h>
#include <hip/hip_bf16.h>
#include <stdint.h>

// B=8192, D=2048, M=8, C=1000; padded: CPAD=1024, NPAD=8192 (n' = c*8 + m)
#define BDIM 8192
#define DDIM 2048
#define MDIM 8
#define CDIM 1000
#define CPAD 1024
#define NPAD 8192

typedef __attribute__((ext_vector_type(8))) short bf16x8;
typedef __attribute__((ext_vector_type(4))) float f32x4;

__device__ __forceinline__ unsigned short f2bf(float f) {
    union { float f; unsigned u; } v; v.f = f;
    unsigned r = v.u + 0x7fffu + ((v.u >> 16) & 1u);   // RNE
    return (unsigned short)(r >> 16);
}

__device__ __forceinline__ void gl_lds16(const void* g, void* l) {
    __builtin_amdgcn_global_load_lds(
        (const __attribute__((address_space(1))) void*)g,
        (__attribute__((address_space(3))) void*)l,
        16, 0, 0);
}

// ---------------- prep: cast x (fp32 -> bf16) ----------------
__global__ void cast_x_kernel(const float4* __restrict__ x, ushort* __restrict__ xb) {
    int i = blockIdx.x * blockDim.x + threadIdx.x;
    float4 v = x[i];
    ushort4 o;
    o.x = f2bf(v.x); o.y = f2bf(v.y); o.z = f2bf(v.z); o.w = f2bf(v.w);
    *(ushort4*)&xb[(size_t)i * 4] = o;
}

// ---- prep: model_weights (M,D,C) -> wb[n'=c*8+m][d], zero-pad c>=1000 ----
__global__ void prep_w(const float* __restrict__ MW, ushort* __restrict__ wb) {
    __shared__ float tile[32][33];
    int m  = blockIdx.z;
    int c0 = blockIdx.x * 32;
    int d0 = blockIdx.y * 32;
    int tx = threadIdx.x, ty = threadIdx.y;
    const float* src = MW + (size_t)m * DDIM * CDIM;
#pragma unroll
    for (int i = 0; i < 4; i++) {
        int d = d0 + ty + i * 8;
        int c = c0 + tx;
        tile[ty + i * 8][tx] = (c < CDIM) ? src[(size_t)d * CDIM + c] : 0.f;
    }
    __syncthreads();
#pragma unroll
    for (int i = 0; i < 4; i++) {
        int c = c0 + ty + i * 8;
        int d = d0 + tx;
        wb[(size_t)(c * 8 + m) * DDIM + d] = f2bf(tile[tx][ty + i * 8]);
    }
}

// ---- prep: resnet_weight (D, 8000) -> rb[n'=c*8+m][d], zero-pad c>=1000 ----
__global__ void prep_r(const float* __restrict__ R, ushort* __restrict__ rb) {
    __shared__ float tile[32][33];
    int m  = blockIdx.z;
    int c0 = blockIdx.x * 32;
    int d0 = blockIdx.y * 32;
    int tx = threadIdx.x, ty = threadIdx.y;
#pragma unroll
    for (int i = 0; i < 4; i++) {
        int d = d0 + ty + i * 8;
        int c = c0 + tx;
        tile[ty + i * 8][tx] = (c < CDIM) ? R[(size_t)d * (MDIM * CDIM) + m * CDIM + c] : 0.f;
    }
    __syncthreads();
#pragma unroll
    for (int i = 0; i < 4; i++) {
        int c = c0 + ty + i * 8;
        int d = d0 + tx;
        rb[(size_t)(c * 8 + m) * DDIM + d] = f2bf(tile[tx][ty + i * 8]);
    }
}

// ---- prep: biases -> interleaved padded float arrays [NPAD] ----
__global__ void prep_bias(const float* __restrict__ mb, const float* __restrict__ rbv,
                          float* __restrict__ mb2, float* __restrict__ rb2) {
    int n = blockIdx.x * 256 + threadIdx.x;   // 0..8191
    int c = n >> 3, m = n & 7;
    mb2[n] = (c < CDIM) ? mb[m * CDIM + c] : 0.f;
    rb2[n] = (c < CDIM) ? rbv[m * CDIM + c] : 0.f;
}

// --- fused dual-B GEMM: BK=32, 64KB LDS, 2 blocks/CU, 2-phase K-tile ---
#define BM 256
#define BN 128
#define BK 32
#define NT (DDIM / BK)   // 64

// Row-major LDS rows of 32 ushorts (64B = 4 x 16B chunks).
// Swizzle: slot = cc ^ ((row>>1)&3)  -> 8 bank-slot positions x 2-way per
// 16-lane group (free). Staged via inverse-swizzled global source.

// A-unit: 256 rows x 32 ushorts = 16KB, 2 insts/thread.
#define STAGE_A(G, L) do {                                                     \
    _Pragma("unroll")                                                          \
    for (int it_ = 0; it_ < 2; ++it_) {                                        \
        int ci_ = it_ * 512 + tid;                                             \
        int r_ = ci_ >> 2, cc_ = ci_ & 3;                                      \
        gl_lds16((G) + (size_t)r_ * DDIM + (size_t)((cc_ ^ ((r_ >> 1) & 3)) << 3), \
                 (L) + (size_t)(it_ * 512 + wbase) * 8);                       \
    }                                                                          \
} while (0)

// B-unit: 128 rows x 32 ushorts = 8KB, 1 inst/thread.
#define STAGE_B(G, L) do {                                                     \
    int r_ = tid >> 2, cc_ = tid & 3;                                          \
    gl_lds16((G) + (size_t)r_ * DDIM + (size_t)((cc_ ^ ((r_ >> 1) & 3)) << 3), \
             (L) + (size_t)wbase * 8);                                         \
} while (0)

// A frags for row-half H (4 x 16-row frags); 16x16x32: cc = lane>>4.
#define LDA4(AC, H) do {                                                       \
    _Pragma("unroll")                                                          \
    for (int i_ = 0; i_ < 4; i_++) {                                           \
        int row_ = wm * 128 + (H) * 64 + i_ * 16 + (lane & 15);                \
        int cc_ = lane >> 4;                                                   \
        af[i_] = *(const bf16x8*)&(AC)[row_ * BK + ((cc_ ^ ((row_ >> 1) & 3)) << 3)]; \
    }                                                                          \
} while (0)

#define LDB2(BS, BF) do {                                                      \
    _Pragma("unroll")                                                          \
    for (int j_ = 0; j_ < 2; j_++) {                                           \
        int row_ = wn * 32 + j_ * 16 + (lane & 15);                            \
        int cc_ = lane >> 4;                                                   \
        BF[j_] = *(const bf16x8*)&(BS)[row_ * BK + ((cc_ ^ ((row_ >> 1) & 3)) << 3)]; \
    }                                                                          \
} while (0)

// 16 MFMA: both accs, row-half H (frags 0-3 of af), both j
#define MM16(H) do {                                                           \
    __builtin_amdgcn_s_setprio(1);                                             \
    _Pragma("unroll")                                                          \
    for (int i_ = 0; i_ < 4; i_++)                                             \
    _Pragma("unroll")                                                          \
    for (int j_ = 0; j_ < 2; j_++) {                                           \
        acc1[(H) * 4 + i_][j_] = __builtin_amdgcn_mfma_f32_16x16x32_bf16(      \
            af[i_], bf1[j_], acc1[(H) * 4 + i_][j_], 0, 0, 0);                 \
        acc2[(H) * 4 + i_][j_] = __builtin_amdgcn_mfma_f32_16x16x32_bf16(      \
            af[i_], bf2[j_], acc2[(H) * 4 + i_][j_], 0, 0, 0);                 \
    }                                                                          \
    __builtin_amdgcn_s_setprio(0);                                             \
} while (0)

#define FENCE() asm volatile("" ::: "memory")
#define BARRIER() do { FENCE(); __builtin_amdgcn_s_barrier(); FENCE(); } while (0)
#define WAITV(N) asm volatile("s_waitcnt vmcnt(" #N ")" ::: "memory")

__global__ __launch_bounds__(512, 2) void gemm_fused(
    const ushort* __restrict__ xb, const ushort* __restrict__ wb,
    const ushort* __restrict__ rb,
    const float* __restrict__ mb2, const float* __restrict__ rb2,
    float* __restrict__ out) {
    __shared__ ushort As[2][BM * BK];    // 2 x 16 KB
    __shared__ ushort B1s[2][BN * BK];   // 2 x 8 KB
    __shared__ ushort B2s[2][BN * BK];   // 2 x 8 KB   -> 64 KB total

    int tid   = threadIdx.x;
    int lane  = tid & 63;
    int wid   = tid >> 6;        // 0..7
    int wm    = wid >> 2;        // 0..1 -> 128-row half
    int wn    = wid & 3;         // 0..3 -> 32-col quarter
    int wbase = tid & ~63;

    // T1: bijective XCD swizzle (2048 % 8 == 0)
    int wg = blockIdx.x;
    int wgs = (wg & 7) * 256 + (wg >> 3);
    int tile_m = wgs >> 6;       // 0..31
    int tile_n = wgs & 63;       // 0..63
    int brow = tile_m * BM;
    int bn0  = tile_n * BN;

    const ushort* xg  = xb + (size_t)brow * DDIM;
    const ushort* w1g = wb + (size_t)bn0 * DDIM;
    const ushort* w2g = rb + (size_t)bn0 * DDIM;

    f32x4 acc1[8][2] = {};
    f32x4 acc2[8][2] = {};
    bf16x8 af[4], bf1[2], bf2[2];

    // Units/K-tile: A (2 insts), B1 (1), B2 (1).
    // Prologue: A(0),B1(0),B2(0),A(1); drain all but A(1).
    STAGE_A(xg,        As[0]);
    STAGE_B(w1g,       B1s[0]);
    STAGE_B(w2g,       B2s[0]);
    STAGE_A(xg + BK,   As[1]);
    WAITV(2);                 // leaves [A(1)] — loop invariant
    BARRIER();

    // Per K-tile t (invariant at top: outstanding = A(t+1), 2 insts):
    //  P1: read af-h0(4), bf1(2), bf2(2) | stage B1,B2(t+1) | bar | 16 MFMA | bar
    //  P2: read af-h1(4)                 | stage A(t+2)     | bar | 16 MFMA
    //      | WAITV(2): drains A(t+1),B1(t+1),B2(t+1), leaves A(t+2) | bar
    // Tail stages read in-bounds garbage (tiles NT/NT+1), never consumed.
#pragma unroll 2
    for (int t = 0; t < NT; ++t) {
        int buf = t & 1;
        ushort* Ac  = As[buf];
        ushort* B1c = B1s[buf];
        ushort* B2c = B2s[buf];
        ushort* B1n = B1s[buf ^ 1];
        ushort* B2n = B2s[buf ^ 1];
        const int kn  = (t + 1) * BK;
        const int kn2 = (t + 2) * BK;

        // P1
        LDA4(Ac, 0);
        LDB2(B1c, bf1);
        LDB2(B2c, bf2);
        STAGE_B(w1g + kn, B1n);
        STAGE_B(w2g + kn, B2n);
        BARRIER();
        MM16(0);
        BARRIER();

        // P2
        LDA4(Ac, 1);
        STAGE_A(xg + kn2, Ac);   // A(t+2) overwrites As[buf]; safe: all tile-t
                                 // A-reads retired before end of P1's MFMA
        BARRIER();
        MM16(1);
        WAITV(2);                // drains A(t+1),B1(t+1),B2(t+1)
        BARRIER();
    }
    WAITV(0);  // garbage-stage DMA must not outlive this workgroup's LDS

    // ---- epilogue: p = (acc1+b1)(acc2+b2); reduce over m (8 adjacent n');
    // n' = c*8 + m -> 3x shfl_xor; plain stores, disjoint per block.
    // acc rf = H*4+i -> tile row = wm*128 + rf*16 + frag row ----
#pragma unroll
    for (int j = 0; j < 2; j++) {
        int np = bn0 + wn * 32 + j * 16 + (lane & 15);
        float bb1 = mb2[np];
        float bb2 = rb2[np];
        int c = tile_n * 16 + wn * 4 + j * 2 + ((lane >> 3) & 1);
#pragma unroll
        for (int rf = 0; rf < 8; rf++) {
#pragma unroll
            for (int r = 0; r < 4; r++) {
                float p = (acc1[rf][j][r] + bb1) * (acc2[rf][j][r] + bb2);
                p += __shfl_xor(p, 1);
                p += __shfl_xor(p, 2);
                p += __shfl_xor(p, 4);
                if ((lane & 7) == 0 && c < CDIM) {
                    int row = brow + wm * 128 + rf * 16 + ((lane >> 4) << 2) + r;
                    out[(size_t)row * CDIM + c] = p;
                }
            }
        }
    }
}

extern "C" void kernel_launch(void* const* d_in, const int* in_sizes, int n_in,
                              void* d_out, int out_size, void* d_ws, size_t ws_size,
                              hipStream_t stream) {
    const float* x   = (const float*)d_in[0];   // [8192][2048]
    const float* mw  = (const float*)d_in[1];   // [8][2048][1000]
    const float* mb  = (const float*)d_in[2];   // [8][1000]
    const float* rw  = (const float*)d_in[3];   // [2048][8000]
    const float* rbv = (const float*)d_in[4];   // [8000]
    float* out = (float*)d_out;                 // [8192][1000]

    char* ws = (char*)d_ws;
    ushort* xb  = (ushort*)ws;                                  // 33,554,432 B
    ushort* wb  = (ushort*)(ws + (size_t)33554432);             // 33,554,432 B
    ushort* rb  = (ushort*)(ws + (size_t)67108864);             // 33,554,432 B
    float*  mb2 = (float*)(ws + (size_t)100663296);             // 32,768 B
    float*  rb2 = (float*)(ws + (size_t)100696064);             // 32,768 B

    cast_x_kernel<<<BDIM * DDIM / (256 * 4), 256, 0, stream>>>((const float4*)x, xb);
    prep_w<<<dim3(CPAD / 32, DDIM / 32, MDIM), dim3(32, 8), 0, stream>>>(mw, wb);
    prep_r<<<dim3(CPAD / 32, DDIM / 32, MDIM), dim3(32, 8), 0, stream>>>(rw, rb);
    prep_bias<<<NPAD / 256, 256, 0, stream>>>(mb, rbv, mb2, rb2);

    gemm_fused<<<dim3((BDIM / BM) * (NPAD / BN)), 512, 0, stream>>>(xb, wb, rb, mb2, rb2, out);
}